// Round 1
// baseline (370.508 us; speedup 1.0000x reference)
//
#include <hip/hip_runtime.h>
#include <math.h>

#define NB 4
#define C_IN 256
#define CKC 64
#define HWSZ 4096   // 64*64
#define K2 25
#define NOCP 36     // 33 output chans padded to 36 (9 float4)

// workspace layout (float offsets)
#define WS_CX    0
#define WS_OFF   (WS_CX + NB*CKC*HWSZ)          // 1048576
#define WS_MASK  (WS_OFF + NB*8*HWSZ)           // +131072
#define WS_WT    (WS_MASK + NB*K2*HWSZ)         // +409600

// ---------------- Kernel A: 1x1 compressor conv ----------------
// grid 256 blocks x 512 thr; block = 64 spatial pos, 8 waves x 8 ck each
__global__ __launch_bounds__(512) void k_compress(const float* __restrict__ x,
    const float* __restrict__ wc, const float* __restrict__ bc,
    float* __restrict__ cx) {
  int t = threadIdx.x;
  int pos = blockIdx.x * 64 + (t & 63);
  int ck0 = __builtin_amdgcn_readfirstlane((t >> 6) * 8);  // wave-uniform -> s_loads
  int n = pos >> 12, hw = pos & 4095;
  const float* xp = x + n * (C_IN * HWSZ) + hw;
  float acc[8];
  #pragma unroll
  for (int i = 0; i < 8; i++) acc[i] = bc[ck0 + i];
  #pragma unroll 4
  for (int c = 0; c < C_IN; c++) {
    float v = xp[c * HWSZ];
    #pragma unroll
    for (int i = 0; i < 8; i++) acc[i] += v * wc[(ck0 + i) * C_IN + c];
  }
  float* o = cx + n * (CKC * HWSZ) + hw;
  #pragma unroll
  for (int i = 0; i < 8; i++) o[(ck0 + i) * HWSZ] = acc[i];
}

// ---------------- Kernel D: transpose conv weights to [c][tap][oc(36)] ----
__global__ void k_wt(const float* __restrict__ wk, const float* __restrict__ wo,
                     float* __restrict__ wT) {
  int i = blockIdx.x * 256 + threadIdx.x;
  if (i >= NOCP * CKC * 9) return;
  int oc = i % NOCP;
  int r = i / NOCP;        // r = c*9 + tap
  int tap = r % 9, c = r / 9;
  float v = 0.f;
  if (oc < 8)       v = wo[(oc * CKC + c) * 9 + tap];
  else if (oc < 33) v = wk[((oc - 8) * CKC + c) * 9 + tap];
  wT[i] = v;
}

// ---------------- Kernel B: fused 3x3 convs (offset 8ch + mask 25ch) + softmax
// grid (128,4): 8x4 spatial tiles; 256 thr = 32 pos x 8 c-groups
__global__ __launch_bounds__(256, 2) void k_convsm(const float* __restrict__ cx,
    const float* __restrict__ wT, const float* __restrict__ bk, const float* __restrict__ bo,
    float* __restrict__ offb, float* __restrict__ maskb) {
  __shared__ float4 red[8 * 32 * 9];
  int t = threadIdx.x;
  int n = blockIdx.y;
  int tile = blockIdx.x;        // tx 0..7 (x8 wide), ty 0..15 (x4 tall)
  int tx = tile & 7, ty = tile >> 3;
  int p = t & 31, cg = t >> 5;
  int yy = ty * 4 + (p >> 3), xx = tx * 8 + (p & 7);
  float4 acc[9];
  #pragma unroll
  for (int j = 0; j < 9; j++) acc[j] = make_float4(0.f, 0.f, 0.f, 0.f);
  const float* cxn = cx + n * (CKC * HWSZ);
  for (int i = 0; i < 8; i++) {
    int c = cg * 8 + i;
    const float* base = cxn + c * HWSZ;
    #pragma unroll
    for (int dy = -1; dy <= 1; dy++) {
      int y2 = yy + dy;
      bool yok = (unsigned)y2 < 64u;
      #pragma unroll
      for (int dx = -1; dx <= 1; dx++) {
        int x2 = xx + dx;
        float v = (yok && (unsigned)x2 < 64u) ? base[y2 * 64 + x2] : 0.f;
        int tap = (dy + 1) * 3 + (dx + 1);
        const float4* wp = (const float4*)(wT + (c * 9 + tap) * NOCP);
        #pragma unroll
        for (int j = 0; j < 9; j++) {
          float4 w4 = wp[j];
          acc[j].x += v * w4.x; acc[j].y += v * w4.y;
          acc[j].z += v * w4.z; acc[j].w += v * w4.w;
        }
      }
    }
  }
  #pragma unroll
  for (int j = 0; j < 9; j++) red[(cg * 32 + p) * 9 + j] = acc[j];
  __syncthreads();
  if (t < 32) {
    float tot[NOCP];
    #pragma unroll
    for (int q = 0; q < NOCP; q++) tot[q] = 0.f;
    for (int g = 0; g < 8; g++) {
      #pragma unroll
      for (int j = 0; j < 9; j++) {
        float4 v = red[(g * 32 + t) * 9 + j];
        tot[j * 4 + 0] += v.x; tot[j * 4 + 1] += v.y;
        tot[j * 4 + 2] += v.z; tot[j * 4 + 3] += v.w;
      }
    }
    int hw = (ty * 4 + (t >> 3)) * 64 + tx * 8 + (t & 7);
    #pragma unroll
    for (int oc = 0; oc < 8; oc++)
      offb[(n * 8 + oc) * HWSZ + hw] = tot[oc] + bo[oc];
    float m[25]; float mx = -1e30f;
    #pragma unroll
    for (int k = 0; k < 25; k++) { m[k] = tot[8 + k] + bk[k]; mx = fmaxf(mx, m[k]); }
    float s = 0.f;
    #pragma unroll
    for (int k = 0; k < 25; k++) { m[k] = __expf(m[k] - mx); s += m[k]; }
    float inv = 1.f / s;
    #pragma unroll
    for (int k = 0; k < 25; k++) maskb[(n * 25 + k) * HWSZ + hw] = m[k] * inv;
  }
}

// ---------------- Kernel C: main CARAFE reassembly ----------------
// 512 blocks x 256 thr. Block = (n, a, wq): h in {a,a+16}, w in [16wq,16wq+16),
// all 4 u, all 256 c -> exactly one output row y across 256 channels.
__global__ __launch_bounds__(256, 2) void k_carafe(const float* __restrict__ x,
    const float* __restrict__ offb, const float* __restrict__ maskb,
    float* __restrict__ out) {
  __attribute__((aligned(16))) __shared__ float s_patch[64 * 201]; // aliased as out stage [128][65]
  __attribute__((aligned(16))) __shared__ float s_kern[32 * 25 * 4];
  int t = threadIdx.x;
  int b = blockIdx.x;
  int n = b >> 7;
  int r = b & 127;
  int wq = r & 3;
  int aa = r >> 2;
  int a = aa + (aa & 16);                 // h base: bit4 == 0
  int yout = (a & 15) * 8 + wq * 2 + ((a >> 5) & 1);
  int w0 = wq * 16;

  // Phase 1: per-(pos,u) 25 resampled kernel weights -> LDS [p][tap][u]
  if (t < 128) {
    int p = t >> 2, u = t & 3;
    int hb = p >> 4, wl = p & 15;
    int h = a + hb * 16;
    int wcol = w0 + wl;
    float ox = offb[(n * 8 + u) * HWSZ + h * 64 + wcol];
    float oy = offb[(n * 8 + 4 + u) * HWSZ + h * 64 + wcol];
    float gx = fminf(fmaxf((float)wcol + ox, 0.f), 63.f);
    float gy = fminf(fmaxf((float)h + oy, 0.f), 63.f);
    float fx0 = floorf(gx), fy0 = floorf(gy);
    int x0 = (int)fx0, y0 = (int)fy0;
    float fx = gx - fx0, fy = gy - fy0;
    int x1 = min(x0 + 1, 63), y1 = min(y0 + 1, 63);
    float w11 = fx * fy;
    float w10 = fy - w11, w01 = fx - w11, w00 = 1.f - fx - fy + w11;
    const float* mb = maskb + n * (K2 * HWSZ);
    int i00 = y0 * 64 + x0, i01 = y0 * 64 + x1;
    int i10 = y1 * 64 + x0, i11 = y1 * 64 + x1;
    #pragma unroll 5
    for (int k = 0; k < 25; k++) {
      const float* mk = mb + k * HWSZ;
      float v = w00 * mk[i00] + w01 * mk[i01] + w10 * mk[i10] + w11 * mk[i11];
      s_kern[(p * 25 + k) * 4 + u] = v;
    }
  }

  int cl = t & 63, g = t >> 6;
  float* s_out = s_patch;                 // alias (12864 >= 128*65)

  for (int cc = 0; cc < 4; cc++) {
    __syncthreads();   // covers phase-1 (first iter) and staging-vs-store alias (later)
    // stage x patch: 64 c x 10 rows x 20 cols, zero-padded, stride 201
    const float* xn = x + (size_t)(n * C_IN + cc * 64) * HWSZ;
    for (int idx = t; idx < 12800; idx += 256) {
      int c = idx / 200;
      int rem = idx - c * 200;
      int rg = rem / 20;
      int col = rem - rg * 20;
      int row = (rg < 5) ? (a - 2 + rg) : (a + 9 + rg);
      int gc = w0 - 2 + col;
      float v = 0.f;
      if ((unsigned)row < 64u && (unsigned)gc < 64u)
        v = xn[c * HWSZ + row * 64 + gc];
      s_patch[c * 201 + rem] = v;
    }
    __syncthreads();
    // compute: thread (c, g) -> 8 positions x 4 u
    float acc[8][4];
    #pragma unroll
    for (int i = 0; i < 8; i++)
      acc[i][0] = acc[i][1] = acc[i][2] = acc[i][3] = 0.f;
    const float* pc = s_patch + cl * 201;
    #pragma unroll
    for (int pr = 0; pr < 8; pr++) {
      int p = g * 8 + pr;
      int hb = p >> 4, wl = p & 15;
      const float* prow = pc + hb * 100 + wl;
      const float4* kp = (const float4*)(s_kern + p * 100);
      #pragma unroll
      for (int dy = 0; dy < 5; dy++) {
        #pragma unroll
        for (int dx = 0; dx < 5; dx++) {
          float f = prow[dy * 20 + dx];
          float4 k4 = kp[dy * 5 + dx];
          acc[pr][0] += f * k4.x;
          acc[pr][1] += f * k4.y;
          acc[pr][2] += f * k4.z;
          acc[pr][3] += f * k4.w;
        }
      }
    }
    __syncthreads();
    // transpose through LDS: s_out[x][c], x = wl*8 + u*2 + hb
    #pragma unroll
    for (int pr = 0; pr < 8; pr++) {
      int p = g * 8 + pr;
      int hb = p >> 4, wl = p & 15;
      #pragma unroll
      for (int u = 0; u < 4; u++) {
        int xo = wl * 8 + u * 2 + hb;
        s_out[xo * 65 + cl] = acc[pr][u];
      }
    }
    __syncthreads();
    // coalesced store: 64 channel-rows x 128 x at fixed yout
    float* orow = out + ((size_t)(n * 256 + cc * 64) * 128 + yout) * 128;
    #pragma unroll
    for (int k = 0; k < 8; k++) {
      int q = t + k * 256;
      int rowc = q >> 5;        // 0..63 (channel within chunk)
      int col4 = q & 31;        // float4 index within row
      float4 v;
      v.x = s_out[(col4 * 4 + 0) * 65 + rowc];
      v.y = s_out[(col4 * 4 + 1) * 65 + rowc];
      v.z = s_out[(col4 * 4 + 2) * 65 + rowc];
      v.w = s_out[(col4 * 4 + 3) * 65 + rowc];
      *(float4*)(orow + (size_t)rowc * (128 * 128) + col4 * 4) = v;
    }
  }
}

extern "C" void kernel_launch(void* const* d_in, const int* in_sizes, int n_in,
                              void* d_out, int out_size, void* d_ws, size_t ws_size,
                              hipStream_t stream) {
  const float* x      = (const float*)d_in[0];
  const float* w_comp = (const float*)d_in[1];
  const float* b_comp = (const float*)d_in[2];
  const float* w_ker  = (const float*)d_in[3];
  const float* b_ker  = (const float*)d_in[4];
  const float* w_off  = (const float*)d_in[5];
  const float* b_off  = (const float*)d_in[6];
  float* out = (float*)d_out;
  float* ws = (float*)d_ws;
  float* cx    = ws + WS_CX;
  float* offb  = ws + WS_OFF;
  float* maskb = ws + WS_MASK;
  float* wT    = ws + WS_WT;

  hipLaunchKernelGGL(k_wt, dim3(81), dim3(256), 0, stream, w_ker, w_off, wT);
  hipLaunchKernelGGL(k_compress, dim3(256), dim3(512), 0, stream, x, w_comp, b_comp, cx);
  hipLaunchKernelGGL(k_convsm, dim3(128, 4), dim3(256), 0, stream,
                     cx, wT, b_ker, b_off, offb, maskb);
  hipLaunchKernelGGL(k_carafe, dim3(512), dim3(256), 0, stream, x, offb, maskb, out);
}

// Round 6
// 251.215 us; speedup vs baseline: 1.4749x; 1.4749x over previous
//
#include <hip/hip_runtime.h>
#include <math.h>

#define NB 4
#define C_IN 256
#define CKC 64
#define HWSZ 4096   // 64*64
#define K2 25
#define NOCP 36     // 33 output chans padded to 36

// workspace layout (float offsets)
#define WS_CX    0
#define WS_OFF   (WS_CX + NB*CKC*HWSZ)          // 1048576
#define WS_MASK  (WS_OFF + NB*8*HWSZ)           // +131072
#define WS_WT    (WS_MASK + NB*K2*HWSZ)         // +409600

// ---------------- Kernel A: 1x1 compressor conv ----------------
// grid 256 blocks x 512 thr; block = 64 spatial pos, 8 waves x 8 ck each
__global__ __launch_bounds__(512) void k_compress(const float* __restrict__ x,
    const float* __restrict__ wc, const float* __restrict__ bc,
    float* __restrict__ cx) {
  int t = threadIdx.x;
  int pos = blockIdx.x * 64 + (t & 63);
  int ck0 = __builtin_amdgcn_readfirstlane((t >> 6) * 8);  // wave-uniform -> s_loads
  int n = pos >> 12, hw = pos & 4095;
  const float* xp = x + n * (C_IN * HWSZ) + hw;
  float acc[8];
  #pragma unroll
  for (int i = 0; i < 8; i++) acc[i] = bc[ck0 + i];
  #pragma unroll 4
  for (int c = 0; c < C_IN; c++) {
    float v = xp[c * HWSZ];
    #pragma unroll
    for (int i = 0; i < 8; i++) acc[i] += v * wc[(ck0 + i) * C_IN + c];
  }
  float* o = cx + n * (CKC * HWSZ) + hw;
  #pragma unroll
  for (int i = 0; i < 8; i++) o[(ck0 + i) * HWSZ] = acc[i];
}

// ---------------- Kernel D: transpose conv weights to [c][tap][oc(36)] ----
__global__ void k_wt(const float* __restrict__ wk, const float* __restrict__ wo,
                     float* __restrict__ wT) {
  int i = blockIdx.x * 256 + threadIdx.x;
  if (i >= NOCP * CKC * 9) return;
  int oc = i % NOCP;
  int r = i / NOCP;        // r = c*9 + tap
  int tap = r % 9, c = r / 9;
  float v = 0.f;
  if (oc < 8)       v = wo[(oc * CKC + c) * 9 + tap];
  else if (oc < 33) v = wk[((oc - 8) * CKC + c) * 9 + tap];
  wT[i] = v;
}

// ---------------- Kernel B (v2): fused 3x3 convs + softmax ----------------
// grid (64,4): block = one 16x4 spatial tile of one n.
// 256 thr = 64 px x 4 oc-groups; each thread: 9 scalar accumulators.
// cx tile staged in LDS.
__global__ __launch_bounds__(256) void k_convsm(const float* __restrict__ cx,
    const float* __restrict__ wT, const float* __restrict__ bk, const float* __restrict__ bo,
    float* __restrict__ offb, float* __restrict__ maskb) {
  __shared__ float s_tile[64 * 108];   // 64 c x (6 rows x 18 cols) halo tile
  __shared__ float s_res[NOCP * 64];   // [oc][px]
  int t = threadIdx.x;
  int n = blockIdx.y;
  int tile = blockIdx.x;
  int x0 = (tile & 3) * 16, y0 = (tile >> 2) * 4;
  const float* cxn = cx + n * (CKC * HWSZ);

  // stage cx halo tile (zero-padded): 6912 = 27 * 256, no tail
  for (int idx = t; idx < 6912; idx += 256) {
    int c = idx / 108;
    int rem = idx - c * 108;
    int row = rem / 18, col = rem - row * 18;
    int gy = y0 - 1 + row, gx = x0 - 1 + col;
    float v = 0.f;
    if ((unsigned)gy < 64u && (unsigned)gx < 64u) v = cxn[c * HWSZ + gy * 64 + gx];
    s_tile[idx] = v;
  }
  __syncthreads();

  int p = t & 63;
  int px = p & 15, py = p >> 4;
  int g = t >> 6;                      // oc-group (wave-uniform by construction)
  float acc[9];
  #pragma unroll
  for (int j = 0; j < 9; j++) acc[j] = 0.f;
  const float* wg = wT + g * 9;
  for (int c = 0; c < CKC; c++) {
    const float* tl = s_tile + c * 108 + py * 18 + px;
    const float* wc9 = wg + c * 9 * NOCP;
    #pragma unroll
    for (int tap = 0; tap < 9; tap++) {
      int dy = tap / 3, dx = tap % 3;
      float v = tl[dy * 18 + dx];
      const float* w = wc9 + tap * NOCP;
      #pragma unroll
      for (int j = 0; j < 9; j++) acc[j] += v * w[j];
    }
  }
  #pragma unroll
  for (int j = 0; j < 9; j++) s_res[(g * 9 + j) * 64 + p] = acc[j];
  __syncthreads();

  int hw = (y0 + py) * 64 + x0 + px;
  // offsets: 8 channels; oc-group g writes oc = 2g, 2g+1 (coalesced per wave)
  #pragma unroll
  for (int i = 0; i < 2; i++) {
    int oc = g * 2 + i;
    offb[(n * 8 + oc) * HWSZ + hw] = s_res[oc * 64 + p] + bo[oc];
  }
  // softmax over 25 kernel positions: threads 0..63, one pixel per lane
  if (t < 64) {
    float m[25], mx = -1e30f;
    #pragma unroll
    for (int k = 0; k < 25; k++) { m[k] = s_res[(8 + k) * 64 + p] + bk[k]; mx = fmaxf(mx, m[k]); }
    float s = 0.f;
    #pragma unroll
    for (int k = 0; k < 25; k++) { m[k] = __expf(m[k] - mx); s += m[k]; }
    float inv = 1.f / s;
    #pragma unroll
    for (int k = 0; k < 25; k++) maskb[(n * 25 + k) * HWSZ + hw] = m[k] * inv;
  }
}

// ---------------- Kernel C: main CARAFE reassembly ----------------
// 512 blocks x 256 thr. Block = (n, a, wq): h in {a,a+16}, w in [16wq,16wq+16),
// all 4 u, all 256 c -> exactly one output row y across 256 channels.
__global__ __launch_bounds__(256, 2) void k_carafe(const float* __restrict__ x,
    const float* __restrict__ offb, const float* __restrict__ maskb,
    float* __restrict__ out) {
  __attribute__((aligned(16))) __shared__ float s_patch[64 * 201]; // aliased as out stage [128][65]
  __attribute__((aligned(16))) __shared__ float s_kern[32 * 25 * 4];
  int t = threadIdx.x;
  int b = blockIdx.x;
  int n = b >> 7;
  int r = b & 127;
  int wq = r & 3;
  int aa = r >> 2;
  int a = aa + (aa & 16);                 // h base: bit4 == 0
  int yout = (a & 15) * 8 + wq * 2 + ((a >> 5) & 1);
  int w0 = wq * 16;

  // Phase 1: per-(pos,u) 25 resampled kernel weights -> LDS [p][tap][u]
  if (t < 128) {
    int p = t >> 2, u = t & 3;
    int hb = p >> 4, wl = p & 15;
    int h = a + hb * 16;
    int wcol = w0 + wl;
    float ox = offb[(n * 8 + u) * HWSZ + h * 64 + wcol];
    float oy = offb[(n * 8 + 4 + u) * HWSZ + h * 64 + wcol];
    float gx = fminf(fmaxf((float)wcol + ox, 0.f), 63.f);
    float gy = fminf(fmaxf((float)h + oy, 0.f), 63.f);
    float fx0 = floorf(gx), fy0 = floorf(gy);
    int x0 = (int)fx0, y0 = (int)fy0;
    float fx = gx - fx0, fy = gy - fy0;
    int x1 = min(x0 + 1, 63), y1 = min(y0 + 1, 63);
    float w11 = fx * fy;
    float w10 = fy - w11, w01 = fx - w11, w00 = 1.f - fx - fy + w11;
    const float* mb = maskb + n * (K2 * HWSZ);
    int i00 = y0 * 64 + x0, i01 = y0 * 64 + x1;
    int i10 = y1 * 64 + x0, i11 = y1 * 64 + x1;
    #pragma unroll 5
    for (int k = 0; k < 25; k++) {
      const float* mk = mb + k * HWSZ;
      float v = w00 * mk[i00] + w01 * mk[i01] + w10 * mk[i10] + w11 * mk[i11];
      s_kern[(p * 25 + k) * 4 + u] = v;
    }
  }

  int cl = t & 63, g = t >> 6;
  float* s_out = s_patch;                 // alias (12864 >= 128*65)

  for (int cc = 0; cc < 4; cc++) {
    __syncthreads();   // covers phase-1 (first iter) and staging-vs-store alias (later)
    // stage x patch: 64 c x 10 rows x 20 cols, zero-padded, stride 201
    const float* xn = x + (size_t)(n * C_IN + cc * 64) * HWSZ;
    for (int idx = t; idx < 12800; idx += 256) {
      int c = idx / 200;
      int rem = idx - c * 200;
      int rg = rem / 20;
      int col = rem - rg * 20;
      int row = (rg < 5) ? (a - 2 + rg) : (a + 9 + rg);
      int gc = w0 - 2 + col;
      float v = 0.f;
      if ((unsigned)row < 64u && (unsigned)gc < 64u)
        v = xn[c * HWSZ + row * 64 + gc];
      s_patch[c * 201 + rem] = v;
    }
    __syncthreads();
    // compute: thread (c, g) -> 8 positions x 4 u
    float acc[8][4];
    #pragma unroll
    for (int i = 0; i < 8; i++)
      acc[i][0] = acc[i][1] = acc[i][2] = acc[i][3] = 0.f;
    const float* pc = s_patch + cl * 201;
    #pragma unroll
    for (int pr = 0; pr < 8; pr++) {
      int p = g * 8 + pr;
      int hb = p >> 4, wl = p & 15;
      const float* prow = pc + hb * 100 + wl;
      const float4* kp = (const float4*)(s_kern + p * 100);
      #pragma unroll
      for (int dy = 0; dy < 5; dy++) {
        #pragma unroll
        for (int dx = 0; dx < 5; dx++) {
          float f = prow[dy * 20 + dx];
          float4 k4 = kp[dy * 5 + dx];
          acc[pr][0] += f * k4.x;
          acc[pr][1] += f * k4.y;
          acc[pr][2] += f * k4.z;
          acc[pr][3] += f * k4.w;
        }
      }
    }
    __syncthreads();
    // transpose through LDS: s_out[x][c], x = wl*8 + u*2 + hb
    #pragma unroll
    for (int pr = 0; pr < 8; pr++) {
      int p = g * 8 + pr;
      int hb = p >> 4, wl = p & 15;
      #pragma unroll
      for (int u = 0; u < 4; u++) {
        int xo = wl * 8 + u * 2 + hb;
        s_out[xo * 65 + cl] = acc[pr][u];
      }
    }
    __syncthreads();
    // coalesced store: 64 channel-rows x 128 x at fixed yout
    float* orow = out + ((size_t)(n * 256 + cc * 64) * 128 + yout) * 128;
    #pragma unroll
    for (int k = 0; k < 8; k++) {
      int q = t + k * 256;
      int rowc = q >> 5;        // 0..63 (channel within chunk)
      int col4 = q & 31;        // float4 index within row
      float4 v;
      v.x = s_out[(col4 * 4 + 0) * 65 + rowc];
      v.y = s_out[(col4 * 4 + 1) * 65 + rowc];
      v.z = s_out[(col4 * 4 + 2) * 65 + rowc];
      v.w = s_out[(col4 * 4 + 3) * 65 + rowc];
      *(float4*)(orow + (size_t)rowc * (128 * 128) + col4 * 4) = v;
    }
  }
}

extern "C" void kernel_launch(void* const* d_in, const int* in_sizes, int n_in,
                              void* d_out, int out_size, void* d_ws, size_t ws_size,
                              hipStream_t stream) {
  const float* x      = (const float*)d_in[0];
  const float* w_comp = (const float*)d_in[1];
  const float* b_comp = (const float*)d_in[2];
  const float* w_ker  = (const float*)d_in[3];
  const float* b_ker  = (const float*)d_in[4];
  const float* w_off  = (const float*)d_in[5];
  const float* b_off  = (const float*)d_in[6];
  float* out = (float*)d_out;
  float* ws = (float*)d_ws;
  float* cx    = ws + WS_CX;
  float* offb  = ws + WS_OFF;
  float* maskb = ws + WS_MASK;
  float* wT    = ws + WS_WT;

  hipLaunchKernelGGL(k_wt, dim3(81), dim3(256), 0, stream, w_ker, w_off, wT);
  hipLaunchKernelGGL(k_compress, dim3(256), dim3(512), 0, stream, x, w_comp, b_comp, cx);
  hipLaunchKernelGGL(k_convsm, dim3(64, 4), dim3(256), 0, stream,
                     cx, wT, b_ker, b_off, offb, maskb);
  hipLaunchKernelGGL(k_carafe, dim3(512), dim3(256), 0, stream, x, offb, maskb, out);
}

// Round 7
// 218.579 us; speedup vs baseline: 1.6951x; 1.1493x over previous
//
#include <hip/hip_runtime.h>
#include <math.h>

#define NB 4
#define C_IN 256
#define CKC 64
#define HWSZ 4096   // 64*64
#define K2 25
#define NOCP 36     // 33 output chans padded to 36

// workspace layout (float offsets)
#define WS_CX    0
#define WS_OFF   (WS_CX + NB*CKC*HWSZ)          // 1048576
#define WS_MASK  (WS_OFF + NB*8*HWSZ)           // +131072
#define WS_WT    (WS_MASK + NB*K2*HWSZ)         // +409600

// ---------------- Kernel A: 1x1 compressor conv ----------------
// grid 256 blocks x 512 thr; block = 64 spatial pos, 8 waves x 8 ck each
__global__ __launch_bounds__(512) void k_compress(const float* __restrict__ x,
    const float* __restrict__ wc, const float* __restrict__ bc,
    float* __restrict__ cx) {
  int t = threadIdx.x;
  int pos = blockIdx.x * 64 + (t & 63);
  int ck0 = __builtin_amdgcn_readfirstlane((t >> 6) * 8);  // wave-uniform -> s_loads
  int n = pos >> 12, hw = pos & 4095;
  const float* xp = x + n * (C_IN * HWSZ) + hw;
  float acc[8];
  #pragma unroll
  for (int i = 0; i < 8; i++) acc[i] = bc[ck0 + i];
  #pragma unroll 4
  for (int c = 0; c < C_IN; c++) {
    float v = xp[c * HWSZ];
    #pragma unroll
    for (int i = 0; i < 8; i++) acc[i] += v * wc[(ck0 + i) * C_IN + c];
  }
  float* o = cx + n * (CKC * HWSZ) + hw;
  #pragma unroll
  for (int i = 0; i < 8; i++) o[(ck0 + i) * HWSZ] = acc[i];
}

// ---------------- Kernel D: transpose conv weights to [c][tap][oc(36)] ----
__global__ void k_wt(const float* __restrict__ wk, const float* __restrict__ wo,
                     float* __restrict__ wT) {
  int i = blockIdx.x * 256 + threadIdx.x;
  if (i >= NOCP * CKC * 9) return;
  int oc = i % NOCP;
  int r = i / NOCP;        // r = c*9 + tap
  int tap = r % 9, c = r / 9;
  float v = 0.f;
  if (oc < 8)       v = wo[(oc * CKC + c) * 9 + tap];
  else if (oc < 33) v = wk[((oc - 8) * CKC + c) * 9 + tap];
  wT[i] = v;
}

// ---------------- Kernel B (v2): fused 3x3 convs + softmax ----------------
// grid (64,4): block = one 16x4 spatial tile of one n.
// 256 thr = 64 px x 4 oc-groups; each thread: 9 scalar accumulators.
// cx tile staged in LDS.
__global__ __launch_bounds__(256) void k_convsm(const float* __restrict__ cx,
    const float* __restrict__ wT, const float* __restrict__ bk, const float* __restrict__ bo,
    float* __restrict__ offb, float* __restrict__ maskb) {
  __shared__ float s_tile[64 * 108];   // 64 c x (6 rows x 18 cols) halo tile
  __shared__ float s_res[NOCP * 64];   // [oc][px]
  int t = threadIdx.x;
  int n = blockIdx.y;
  int tile = blockIdx.x;
  int x0 = (tile & 3) * 16, y0 = (tile >> 2) * 4;
  const float* cxn = cx + n * (CKC * HWSZ);

  // stage cx halo tile (zero-padded): 6912 = 27 * 256, no tail
  for (int idx = t; idx < 6912; idx += 256) {
    int c = idx / 108;
    int rem = idx - c * 108;
    int row = rem / 18, col = rem - row * 18;
    int gy = y0 - 1 + row, gx = x0 - 1 + col;
    float v = 0.f;
    if ((unsigned)gy < 64u && (unsigned)gx < 64u) v = cxn[c * HWSZ + gy * 64 + gx];
    s_tile[idx] = v;
  }
  __syncthreads();

  int p = t & 63;
  int px = p & 15, py = p >> 4;
  int g = t >> 6;                      // oc-group (wave-uniform by construction)
  float acc[9];
  #pragma unroll
  for (int j = 0; j < 9; j++) acc[j] = 0.f;
  const float* wg = wT + g * 9;
  for (int c = 0; c < CKC; c++) {
    const float* tl = s_tile + c * 108 + py * 18 + px;
    const float* wc9 = wg + c * 9 * NOCP;
    #pragma unroll
    for (int tap = 0; tap < 9; tap++) {
      int dy = tap / 3, dx = tap % 3;
      float v = tl[dy * 18 + dx];
      const float* w = wc9 + tap * NOCP;
      #pragma unroll
      for (int j = 0; j < 9; j++) acc[j] += v * w[j];
    }
  }
  #pragma unroll
  for (int j = 0; j < 9; j++) s_res[(g * 9 + j) * 64 + p] = acc[j];
  __syncthreads();

  int hw = (y0 + py) * 64 + x0 + px;
  // offsets: 8 channels; oc-group g writes oc = 2g, 2g+1 (coalesced per wave)
  #pragma unroll
  for (int i = 0; i < 2; i++) {
    int oc = g * 2 + i;
    offb[(n * 8 + oc) * HWSZ + hw] = s_res[oc * 64 + p] + bo[oc];
  }
  // softmax over 25 kernel positions: threads 0..63, one pixel per lane
  if (t < 64) {
    float m[25], mx = -1e30f;
    #pragma unroll
    for (int k = 0; k < 25; k++) { m[k] = s_res[(8 + k) * 64 + p] + bk[k]; mx = fmaxf(mx, m[k]); }
    float s = 0.f;
    #pragma unroll
    for (int k = 0; k < 25; k++) { m[k] = __expf(m[k] - mx); s += m[k]; }
    float inv = 1.f / s;
    #pragma unroll
    for (int k = 0; k < 25; k++) maskb[(n * 25 + k) * HWSZ + hw] = m[k] * inv;
  }
}

// ---------------- Kernel C (v2): main CARAFE reassembly ----------------
// 1024 blocks x 256 thr = 4 blocks/CU (LDS 38.5KB). Block = (n, a, wq, c-half):
// h in {a,a+16}, w in [16wq,16wq+16), all 4 u, 128 channels -> one output
// row y x 128 channels. 32-channel chunks; register row-cache in compute.
__global__ __launch_bounds__(256, 4) void k_carafe(const float* __restrict__ x,
    const float* __restrict__ offb, const float* __restrict__ maskb,
    float* __restrict__ out) {
  __attribute__((aligned(16))) __shared__ float s_patch[32 * 201]; // 25728B; aliased as s_out [32][130]
  __attribute__((aligned(16))) __shared__ float s_kern[32 * 25 * 4]; // 12800B
  int t = threadIdx.x;
  int b = blockIdx.x;
  int n = b >> 8;
  int r = b & 255;
  int half = r & 1;
  int wq = (r >> 1) & 3;
  int aa = r >> 3;
  int a = aa + (aa & 16);                 // h base: bit4 == 0
  int yout = (a & 15) * 8 + wq * 2 + ((a >> 5) & 1);
  int w0 = wq * 16;
  int cbase = n * C_IN + half * 128;

  // Phase 1: per-(pos,u) 25 resampled kernel weights -> LDS [p][tap][u]
  if (t < 128) {
    int p = t >> 2, u = t & 3;
    int hb = p >> 4, wl = p & 15;
    int h = a + hb * 16;
    int wcol = w0 + wl;
    float ox = offb[(n * 8 + u) * HWSZ + h * 64 + wcol];
    float oy = offb[(n * 8 + 4 + u) * HWSZ + h * 64 + wcol];
    float gx = fminf(fmaxf((float)wcol + ox, 0.f), 63.f);
    float gy = fminf(fmaxf((float)h + oy, 0.f), 63.f);
    float fx0 = floorf(gx), fy0 = floorf(gy);
    int x0 = (int)fx0, y0 = (int)fy0;
    float fx = gx - fx0, fy = gy - fy0;
    int x1 = min(x0 + 1, 63), y1 = min(y0 + 1, 63);
    float w11 = fx * fy;
    float w10 = fy - w11, w01 = fx - w11, w00 = 1.f - fx - fy + w11;
    const float* mb = maskb + n * (K2 * HWSZ);
    int i00 = y0 * 64 + x0, i01 = y0 * 64 + x1;
    int i10 = y1 * 64 + x0, i11 = y1 * 64 + x1;
    #pragma unroll 5
    for (int k = 0; k < 25; k++) {
      const float* mk = mb + k * HWSZ;
      float v = w00 * mk[i00] + w01 * mk[i01] + w10 * mk[i10] + w11 * mk[i11];
      s_kern[(p * 25 + k) * 4 + u] = v;
    }
  }

  int cl = t & 31, g = t >> 5;            // channel lane 0..31, pos-group 0..7
  int hb = g >> 2, wl0 = (g & 3) * 4;     // each group: 4 consecutive wl in one hb
  float* s_out = s_patch;                 // alias: [32][130] = 16640B <= 25728B

  for (int cc = 0; cc < 4; cc++) {
    __syncthreads();   // covers phase-1 (first iter) and staging-vs-store alias (later)
    // stage x patch: 32 c x 10 rows x 20 cols, zero-padded, stride 201
    const float* xn = x + (size_t)(cbase + cc * 32) * HWSZ;
    for (int idx = t; idx < 6400; idx += 256) {
      int c = idx / 200;
      int rem = idx - c * 200;
      int rg = rem / 20;
      int col = rem - rg * 20;
      int row = (rg < 5) ? (a - 2 + rg) : (a + 9 + rg);
      int gc = w0 - 2 + col;
      float v = 0.f;
      if ((unsigned)row < 64u && (unsigned)gc < 64u)
        v = xn[c * HWSZ + row * 64 + gc];
      s_patch[c * 201 + rem] = v;
    }
    __syncthreads();
    // compute: thread (cl, g) -> 4 positions x 4 u; register row-cache over dy
    float acc[4][4];
    #pragma unroll
    for (int i = 0; i < 4; i++)
      acc[i][0] = acc[i][1] = acc[i][2] = acc[i][3] = 0.f;
    const float* pc = s_patch + cl * 201 + hb * 100 + wl0;
    #pragma unroll
    for (int dy = 0; dy < 5; dy++) {
      float r8[8];
      #pragma unroll
      for (int j = 0; j < 8; j++) r8[j] = pc[dy * 20 + j];
      #pragma unroll
      for (int pr = 0; pr < 4; pr++) {
        const float4* kp = (const float4*)(s_kern + (((g * 4 + pr) * 25) + dy * 5) * 4);
        #pragma unroll
        for (int dx = 0; dx < 5; dx++) {
          float f = r8[pr + dx];
          float4 k4 = kp[dx];
          acc[pr][0] += f * k4.x;
          acc[pr][1] += f * k4.y;
          acc[pr][2] += f * k4.z;
          acc[pr][3] += f * k4.w;
        }
      }
    }
    __syncthreads();
    // transpose through LDS: s_out[c][x] stride 130, x = wl*8 + u*2 + hb
    #pragma unroll
    for (int pr = 0; pr < 4; pr++) {
      int wl = wl0 + pr;
      #pragma unroll
      for (int u = 0; u < 4; u++) {
        int xo = wl * 8 + u * 2 + hb;
        s_out[cl * 130 + xo] = acc[pr][u];
      }
    }
    __syncthreads();
    // coalesced store: 32 channel-rows x 128 x at fixed yout
    float* obase = out + ((size_t)(cbase + cc * 32) * 128 + yout) * 128;
    #pragma unroll
    for (int it = 0; it < 4; it++) {
      int q = t + it * 256;
      int rowc = q >> 5;        // 0..31 (channel within chunk)
      int col4 = q & 31;        // float4 index within row
      const float* sp = s_out + rowc * 130 + col4 * 4;
      float4 v = make_float4(sp[0], sp[1], sp[2], sp[3]);
      *(float4*)(obase + (size_t)rowc * (128 * 128) + col4 * 4) = v;
    }
  }
}

extern "C" void kernel_launch(void* const* d_in, const int* in_sizes, int n_in,
                              void* d_out, int out_size, void* d_ws, size_t ws_size,
                              hipStream_t stream) {
  const float* x      = (const float*)d_in[0];
  const float* w_comp = (const float*)d_in[1];
  const float* b_comp = (const float*)d_in[2];
  const float* w_ker  = (const float*)d_in[3];
  const float* b_ker  = (const float*)d_in[4];
  const float* w_off  = (const float*)d_in[5];
  const float* b_off  = (const float*)d_in[6];
  float* out = (float*)d_out;
  float* ws = (float*)d_ws;
  float* cx    = ws + WS_CX;
  float* offb  = ws + WS_OFF;
  float* maskb = ws + WS_MASK;
  float* wT    = ws + WS_WT;

  hipLaunchKernelGGL(k_wt, dim3(81), dim3(256), 0, stream, w_ker, w_off, wT);
  hipLaunchKernelGGL(k_compress, dim3(256), dim3(512), 0, stream, x, w_comp, b_comp, cx);
  hipLaunchKernelGGL(k_convsm, dim3(64, 4), dim3(256), 0, stream,
                     cx, wT, b_ker, b_off, offb, maskb);
  hipLaunchKernelGGL(k_carafe, dim3(1024), dim3(256), 0, stream, x, offb, maskb, out);
}

// Round 8
// 206.239 us; speedup vs baseline: 1.7965x; 1.0598x over previous
//
#include <hip/hip_runtime.h>
#include <math.h>

#define NB 4
#define C_IN 256
#define CKC 64
#define HWSZ 4096   // 64*64
#define K2 25
#define NOC2 40     // 33 output chans padded to 40 (8 groups x 5)

// workspace layout (float offsets)
#define WS_CX    0
#define WS_OFF   (WS_CX + NB*CKC*HWSZ)          // 1048576
#define WS_MASK  (WS_OFF + NB*8*HWSZ)           // +131072
#define WS_WT    (WS_MASK + NB*K2*HWSZ)         // +409600
// wcT (16384 floats) overlays WS_MASK: dead until k_convsm writes maskb,
// and k_compress (its only reader) runs before k_convsm.

#define NWT (CKC * 9 * NOC2)    // 23040
#define NWC (C_IN * CKC)        // 16384

// ---------------- Kernel D: weight prep ----------------
// wT[c][tap][oc(40)] for the 3x3 convs; wcT[c][ck] for the compressor.
__global__ void k_wt(const float* __restrict__ wk, const float* __restrict__ wo,
                     const float* __restrict__ wc,
                     float* __restrict__ wT, float* __restrict__ wcT) {
  int i = blockIdx.x * 256 + threadIdx.x;
  if (i < NWT) {
    int oc = i % NOC2;
    int r = i / NOC2;        // r = c*9 + tap
    int tap = r % 9, c = r / 9;
    float v = 0.f;
    if (oc < 8)       v = wo[(oc * CKC + c) * 9 + tap];
    else if (oc < 33) v = wk[((oc - 8) * CKC + c) * 9 + tap];
    wT[i] = v;
  } else {
    int j = i - NWT;
    if (j < NWC) {
      int c = j >> 6, ck = j & 63;
      wcT[j] = wc[ck * C_IN + c];
    }
  }
}

// ---------------- Kernel A (v2): 1x1 compressor as LDS-tiled GEMM ----------
// 256 blocks x 512 thr; block = one 64-pixel row, 8 waves = 8 ck-groups of 8.
// x staged in LDS 64c-chunks; weights via wave-uniform s_load from wcT.
__global__ __launch_bounds__(512) void k_compress(const float* __restrict__ x,
    const float* __restrict__ wcT, const float* __restrict__ bc,
    float* __restrict__ cx) {
  __shared__ float s_x[64 * 64];   // [c][pos] 16KB
  int t = threadIdx.x;
  int pos0 = blockIdx.x * 64;
  int n = pos0 >> 12, hw0 = pos0 & 4095;
  int p = t & 63;
  int g = __builtin_amdgcn_readfirstlane(t >> 6);   // ck-group 0..7, wave-uniform
  const float* xn = x + (size_t)n * (C_IN * HWSZ) + hw0;
  float acc[8];
  #pragma unroll
  for (int i = 0; i < 8; i++) acc[i] = bc[g * 8 + i];
  for (int cc = 0; cc < 4; cc++) {
    __syncthreads();
    #pragma unroll
    for (int it = 0; it < 8; it++) {
      int idx = t + it * 512;
      int c = idx >> 6, pp = idx & 63;
      s_x[idx] = xn[(cc * 64 + c) * HWSZ + pp];
    }
    __syncthreads();
    const float* wbase = wcT + (cc * 64) * 64 + g * 8;
    #pragma unroll 4
    for (int c = 0; c < 64; c++) {
      float v = s_x[c * 64 + p];
      const float* w = wbase + c * 64;
      #pragma unroll
      for (int i = 0; i < 8; i++) acc[i] += v * w[i];
    }
  }
  float* o = cx + (size_t)n * (CKC * HWSZ) + hw0 + p;
  #pragma unroll
  for (int i = 0; i < 8; i++) o[(g * 8 + i) * HWSZ] = acc[i];
}

// ---------------- Kernel B (v3): fused 3x3 convs + softmax ----------------
// grid (64,4) x 512 thr: block = one 16x4 spatial tile; 64 px x 8 oc-groups
// of 5 (NOC2=40). 2 waves/SIMD for latency hiding.
__global__ __launch_bounds__(512) void k_convsm(const float* __restrict__ cx,
    const float* __restrict__ wT, const float* __restrict__ bk, const float* __restrict__ bo,
    float* __restrict__ offb, float* __restrict__ maskb) {
  __shared__ float s_tile[64 * 108];   // 64 c x (6 rows x 18 cols) halo tile
  __shared__ float s_res[NOC2 * 64];   // [oc][px]
  int t = threadIdx.x;
  int n = blockIdx.y;
  int tile = blockIdx.x;
  int x0 = (tile & 3) * 16, y0 = (tile >> 2) * 4;
  const float* cxn = cx + n * (CKC * HWSZ);

  // stage cx halo tile (zero-padded)
  for (int idx = t; idx < 6912; idx += 512) {
    int c = idx / 108;
    int rem = idx - c * 108;
    int row = rem / 18, col = rem - row * 18;
    int gy = y0 - 1 + row, gx = x0 - 1 + col;
    float v = 0.f;
    if ((unsigned)gy < 64u && (unsigned)gx < 64u) v = cxn[c * HWSZ + gy * 64 + gx];
    s_tile[idx] = v;
  }
  __syncthreads();

  int p = t & 63;
  int px = p & 15, py = p >> 4;
  int g = __builtin_amdgcn_readfirstlane(t >> 6);   // oc-group 0..7, wave-uniform
  float acc[5];
  #pragma unroll
  for (int j = 0; j < 5; j++) acc[j] = 0.f;
  const float* wg = wT + g * 5;
  for (int c = 0; c < CKC; c++) {
    const float* tl = s_tile + c * 108 + py * 18 + px;
    const float* wc9 = wg + c * 9 * NOC2;
    #pragma unroll
    for (int tap = 0; tap < 9; tap++) {
      int dy = tap / 3, dx = tap % 3;
      float v = tl[dy * 18 + dx];
      const float* w = wc9 + tap * NOC2;
      #pragma unroll
      for (int j = 0; j < 5; j++) acc[j] += v * w[j];
    }
  }
  #pragma unroll
  for (int j = 0; j < 5; j++) s_res[(g * 5 + j) * 64 + p] = acc[j];
  __syncthreads();

  int hw = (y0 + py) * 64 + x0 + px;
  // offsets: 8 channels; group g writes oc = g (row index == oc)
  offb[(n * 8 + g) * HWSZ + hw] = s_res[g * 64 + p] + bo[g];
  // softmax over 25 kernel positions: threads 0..63, one pixel per lane
  if (t < 64) {
    float m[25], mx = -1e30f;
    #pragma unroll
    for (int k = 0; k < 25; k++) { m[k] = s_res[(8 + k) * 64 + p] + bk[k]; mx = fmaxf(mx, m[k]); }
    float s = 0.f;
    #pragma unroll
    for (int k = 0; k < 25; k++) { m[k] = __expf(m[k] - mx); s += m[k]; }
    float inv = 1.f / s;
    #pragma unroll
    for (int k = 0; k < 25; k++) maskb[(n * 25 + k) * HWSZ + hw] = m[k] * inv;
  }
}

// ---------------- Kernel C (v2): main CARAFE reassembly ----------------
// 1024 blocks x 256 thr = 4 blocks/CU (LDS 38.5KB). Block = (n, a, wq, c-half):
// h in {a,a+16}, w in [16wq,16wq+16), all 4 u, 128 channels -> one output
// row y x 128 channels. 32-channel chunks; register row-cache in compute.
__global__ __launch_bounds__(256, 4) void k_carafe(const float* __restrict__ x,
    const float* __restrict__ offb, const float* __restrict__ maskb,
    float* __restrict__ out) {
  __attribute__((aligned(16))) __shared__ float s_patch[32 * 201]; // 25728B; aliased as s_out [32][130]
  __attribute__((aligned(16))) __shared__ float s_kern[32 * 25 * 4]; // 12800B
  int t = threadIdx.x;
  int b = blockIdx.x;
  int n = b >> 8;
  int r = b & 255;
  int half = r & 1;
  int wq = (r >> 1) & 3;
  int aa = r >> 3;
  int a = aa + (aa & 16);                 // h base: bit4 == 0
  int yout = (a & 15) * 8 + wq * 2 + ((a >> 5) & 1);
  int w0 = wq * 16;
  int cbase = n * C_IN + half * 128;

  // Phase 1: per-(pos,u) 25 resampled kernel weights -> LDS [p][tap][u]
  if (t < 128) {
    int p = t >> 2, u = t & 3;
    int hb = p >> 4, wl = p & 15;
    int h = a + hb * 16;
    int wcol = w0 + wl;
    float ox = offb[(n * 8 + u) * HWSZ + h * 64 + wcol];
    float oy = offb[(n * 8 + 4 + u) * HWSZ + h * 64 + wcol];
    float gx = fminf(fmaxf((float)wcol + ox, 0.f), 63.f);
    float gy = fminf(fmaxf((float)h + oy, 0.f), 63.f);
    float fx0 = floorf(gx), fy0 = floorf(gy);
    int x0 = (int)fx0, y0 = (int)fy0;
    float fx = gx - fx0, fy = gy - fy0;
    int x1 = min(x0 + 1, 63), y1 = min(y0 + 1, 63);
    float w11 = fx * fy;
    float w10 = fy - w11, w01 = fx - w11, w00 = 1.f - fx - fy + w11;
    const float* mb = maskb + n * (K2 * HWSZ);
    int i00 = y0 * 64 + x0, i01 = y0 * 64 + x1;
    int i10 = y1 * 64 + x0, i11 = y1 * 64 + x1;
    #pragma unroll 5
    for (int k = 0; k < 25; k++) {
      const float* mk = mb + k * HWSZ;
      float v = w00 * mk[i00] + w01 * mk[i01] + w10 * mk[i10] + w11 * mk[i11];
      s_kern[(p * 25 + k) * 4 + u] = v;
    }
  }

  int cl = t & 31, g = t >> 5;            // channel lane 0..31, pos-group 0..7
  int hb = g >> 2, wl0 = (g & 3) * 4;     // each group: 4 consecutive wl in one hb
  float* s_out = s_patch;                 // alias: [32][130] = 16640B <= 25728B

  for (int cc = 0; cc < 4; cc++) {
    __syncthreads();   // covers phase-1 (first iter) and staging-vs-store alias (later)
    // stage x patch: 32 c x 10 rows x 20 cols, zero-padded, stride 201
    const float* xn = x + (size_t)(cbase + cc * 32) * HWSZ;
    for (int idx = t; idx < 6400; idx += 256) {
      int c = idx / 200;
      int rem = idx - c * 200;
      int rg = rem / 20;
      int col = rem - rg * 20;
      int row = (rg < 5) ? (a - 2 + rg) : (a + 9 + rg);
      int gc = w0 - 2 + col;
      float v = 0.f;
      if ((unsigned)row < 64u && (unsigned)gc < 64u)
        v = xn[c * HWSZ + row * 64 + gc];
      s_patch[c * 201 + rem] = v;
    }
    __syncthreads();
    // compute: thread (cl, g) -> 4 positions x 4 u; register row-cache over dy
    float acc[4][4];
    #pragma unroll
    for (int i = 0; i < 4; i++)
      acc[i][0] = acc[i][1] = acc[i][2] = acc[i][3] = 0.f;
    const float* pc = s_patch + cl * 201 + hb * 100 + wl0;
    #pragma unroll
    for (int dy = 0; dy < 5; dy++) {
      float r8[8];
      #pragma unroll
      for (int j = 0; j < 8; j++) r8[j] = pc[dy * 20 + j];
      #pragma unroll
      for (int pr = 0; pr < 4; pr++) {
        const float4* kp = (const float4*)(s_kern + (((g * 4 + pr) * 25) + dy * 5) * 4);
        #pragma unroll
        for (int dx = 0; dx < 5; dx++) {
          float f = r8[pr + dx];
          float4 k4 = kp[dx];
          acc[pr][0] += f * k4.x;
          acc[pr][1] += f * k4.y;
          acc[pr][2] += f * k4.z;
          acc[pr][3] += f * k4.w;
        }
      }
    }
    __syncthreads();
    // transpose through LDS: s_out[c][x] stride 130, x = wl*8 + u*2 + hb
    #pragma unroll
    for (int pr = 0; pr < 4; pr++) {
      int wl = wl0 + pr;
      #pragma unroll
      for (int u = 0; u < 4; u++) {
        int xo = wl * 8 + u * 2 + hb;
        s_out[cl * 130 + xo] = acc[pr][u];
      }
    }
    __syncthreads();
    // coalesced store: 32 channel-rows x 128 x at fixed yout
    float* obase = out + ((size_t)(cbase + cc * 32) * 128 + yout) * 128;
    #pragma unroll
    for (int it = 0; it < 4; it++) {
      int q = t + it * 256;
      int rowc = q >> 5;        // 0..31 (channel within chunk)
      int col4 = q & 31;        // float4 index within row
      const float* sp = s_out + rowc * 130 + col4 * 4;
      float4 v = make_float4(sp[0], sp[1], sp[2], sp[3]);
      *(float4*)(obase + (size_t)rowc * (128 * 128) + col4 * 4) = v;
    }
  }
}

extern "C" void kernel_launch(void* const* d_in, const int* in_sizes, int n_in,
                              void* d_out, int out_size, void* d_ws, size_t ws_size,
                              hipStream_t stream) {
  const float* x      = (const float*)d_in[0];
  const float* w_comp = (const float*)d_in[1];
  const float* b_comp = (const float*)d_in[2];
  const float* w_ker  = (const float*)d_in[3];
  const float* b_ker  = (const float*)d_in[4];
  const float* w_off  = (const float*)d_in[5];
  const float* b_off  = (const float*)d_in[6];
  float* out = (float*)d_out;
  float* ws = (float*)d_ws;
  float* cx    = ws + WS_CX;
  float* offb  = ws + WS_OFF;
  float* maskb = ws + WS_MASK;
  float* wT    = ws + WS_WT;
  float* wcT   = ws + WS_MASK;   // temporal overlay: dead before k_convsm writes maskb

  hipLaunchKernelGGL(k_wt, dim3((NWT + NWC + 255) / 256), dim3(256), 0, stream,
                     w_ker, w_off, w_comp, wT, wcT);
  hipLaunchKernelGGL(k_compress, dim3(256), dim3(512), 0, stream, x, wcT, b_comp, cx);
  hipLaunchKernelGGL(k_convsm, dim3(64, 4), dim3(512), 0, stream,
                     cx, wT, b_ker, b_off, offb, maskb);
  hipLaunchKernelGGL(k_carafe, dim3(1024), dim3(256), 0, stream, x, offb, maskb, out);
}